// Round 8
// baseline (4356.672 us; speedup 1.0000x reference)
//
#include <hip/hip_runtime.h>
#include <hip/hip_bf16.h>

#define BB   128   // batch
#define TT   512   // seq len
#define II   256   // input dim
#define HH   512   // hidden dim
#define G3   1536  // 3*H

typedef __attribute__((ext_vector_type(8))) short short8;
typedef __attribute__((ext_vector_type(4))) float f32x4;
typedef __attribute__((ext_vector_type(4))) unsigned int u32x4;

__device__ __forceinline__ float bf2f(unsigned short u) {
    union { unsigned int u; float f; } p; p.u = ((unsigned int)u) << 16; return p.f;
}
__device__ __forceinline__ unsigned short f2bf(float f) {
    union { float f; unsigned int u; } p; p.f = f;
    unsigned int r = p.u + 0x7fffu + ((p.u >> 16) & 1u);  // RNE
    return (unsigned short)(r >> 16);
}
__device__ __forceinline__ float sigmoidf_fast(float x) {
    return 1.0f / (1.0f + __expf(-x));
}
__device__ __forceinline__ float tanhf_fast(float x) {
    return 1.0f - 2.0f / (1.0f + __expf(2.0f * x));
}

// coherent 16B load with literal offset (bypass L1/L2: remote stores visible).
// Caller must s_waitcnt vmcnt(0) + sched_barrier(0) before using dst (rule #18).
#define GLD16O(dst, base, OFFSTR)                                         \
    asm volatile("global_load_dwordx4 %0, %1, off offset:" OFFSTR " sc0 sc1" \
                 : "=v"(dst) : "v"(base))

// ---------------------------------------------------------------------------
// Kernel 1: xg[t][b][g] = bf16( x[b,t,:] @ W_ih[g,:] + b_ih[g] )   (unchanged)
// ---------------------------------------------------------------------------
__global__ __launch_bounds__(256) void xgate_gemm(
    const float* __restrict__ x,       // [B,T,I]
    const float* __restrict__ Wih,     // [1536,256]
    const float* __restrict__ bih,     // [1536]
    unsigned short* __restrict__ xg)   // [T,B,1536] bf16
{
    __shared__ unsigned short AS[128][40];
    __shared__ unsigned short BS[128][40];

    const int t   = blockIdx.y;
    const int g0  = blockIdx.x * 128;
    const int tid = threadIdx.x;
    const int lane = tid & 63;
    const int w    = tid >> 6;
    const int wr   = w >> 1, wc = w & 1;

    f32x4 acc[4][4];
#pragma unroll
    for (int a = 0; a < 4; ++a)
#pragma unroll
        for (int b = 0; b < 4; ++b) acc[a][b] = (f32x4)(0.0f);

    for (int kk = 0; kk < 8; ++kk) {
        const int k0 = kk * 32;
#pragma unroll
        for (int ii = 0; ii < 4; ++ii) {
            int slot = tid + 256 * ii;
            int row  = slot >> 3;
            int c4   = slot & 7;
            float4 av = *(const float4*)(x + ((size_t)row * TT + t) * II + k0 + c4 * 4);
            unsigned short* ap = &AS[row][c4 * 4];
            ap[0] = f2bf(av.x); ap[1] = f2bf(av.y); ap[2] = f2bf(av.z); ap[3] = f2bf(av.w);
            float4 bv = *(const float4*)(Wih + (size_t)(g0 + row) * II + k0 + c4 * 4);
            unsigned short* bp = &BS[row][c4 * 4];
            bp[0] = f2bf(bv.x); bp[1] = f2bf(bv.y); bp[2] = f2bf(bv.z); bp[3] = f2bf(bv.w);
        }
        __syncthreads();

        const int kc = (lane >> 4) * 8;
        short8 a[4], b[4];
#pragma unroll
        for (int mi = 0; mi < 4; ++mi)
            a[mi] = *(const short8*)&AS[wr * 64 + mi * 16 + (lane & 15)][kc];
#pragma unroll
        for (int ni = 0; ni < 4; ++ni)
            b[ni] = *(const short8*)&BS[wc * 64 + ni * 16 + (lane & 15)][kc];
#pragma unroll
        for (int mi = 0; mi < 4; ++mi)
#pragma unroll
            for (int ni = 0; ni < 4; ++ni)
                acc[mi][ni] = __builtin_amdgcn_mfma_f32_16x16x32_bf16(a[mi], b[ni], acc[mi][ni], 0, 0, 0);
        __syncthreads();
    }

#pragma unroll
    for (int ni = 0; ni < 4; ++ni) {
        const int col = wc * 64 + ni * 16 + (lane & 15);
        const float bias = bih[g0 + col];
#pragma unroll
        for (int mi = 0; mi < 4; ++mi) {
#pragma unroll
            for (int i = 0; i < 4; ++i) {
                const int row = wr * 64 + mi * 16 + (lane >> 4) * 4 + i;
                xg[((size_t)t * BB + row) * G3 + g0 + col] = f2bf(acc[mi][ni][i] + bias);
            }
        }
    }
}

// ---------------------------------------------------------------------------
// Kernel 2 v5 (REAL, unchanged from the 1602 us round): 128 blocks x 2 waves.
// ---------------------------------------------------------------------------
#define NTH2 128

__global__ __launch_bounds__(NTH2, 1) void gru_scan(
    const unsigned short* __restrict__ xg,    // [T,B,1536] bf16
    const float* __restrict__ Whh,            // [1536,512]
    const float* __restrict__ bhh,            // [1536]
    float* __restrict__ out,                  // [B,H]
    unsigned long long* __restrict__ hb64)    // [2][B][256] tagged pairs
{
    __shared__ unsigned int hF[2 * 4096];     // 32 KiB, [parity][ks][1024B frag]

    const int g    = blockIdx.x & 7;
    const int m    = blockIdx.x >> 3;
    const int tid  = threadIdx.x;
    const int lane = tid & 63;
    const int w    = tid >> 6;

    const int jj = m * 32 + w * 16 + (lane & 15);
    short8 Wr[3][16];
    {
        const int kofs = (lane >> 4) * 8;
#pragma unroll
        for (int q = 0; q < 3; ++q) {
            const float* wrow = Whh + ((size_t)(q * HH + jj)) * HH + kofs;
#pragma unroll
            for (int ks = 0; ks < 16; ++ks) {
                float4 v0 = *(const float4*)(wrow + ks * 32);
                float4 v1 = *(const float4*)(wrow + ks * 32 + 4);
                union { short8 s; unsigned int u[4]; } pk;
                pk.u[0] = (unsigned int)f2bf(v0.x) | ((unsigned int)f2bf(v0.y) << 16);
                pk.u[1] = (unsigned int)f2bf(v0.z) | ((unsigned int)f2bf(v0.w) << 16);
                pk.u[2] = (unsigned int)f2bf(v1.x) | ((unsigned int)f2bf(v1.y) << 16);
                pk.u[3] = (unsigned int)f2bf(v1.z) | ((unsigned int)f2bf(v1.w) << 16);
                Wr[q][ks] = pk.s;
            }
        }
    }

    const float bhr = bhh[jj];
    const float bhz = bhh[HH + jj];
    const float bhn = bhh[2 * HH + jj];
    const int b0 = (lane >> 4) * 4;

    float hh[4] = {0.0f, 0.0f, 0.0f, 0.0f};

    const int prow = tid & 15;
    const int plg  = (tid >> 4) & 3;
    const int pe2  = tid >> 6;
    const char* pollb = (const char*)hb64 +
        (((size_t)g * 16 + prow) * 256 + plg * 4 + pe2 * 2) * 8;
    const size_t PARITY_B = (size_t)BB * 256 * 8;
    const int dstb = plg * 64 + prow * 4 + pe2 * 2;

    const unsigned int* xg32 = (const unsigned int*)xg;
    const unsigned int xsel = (unsigned int)(jj & 1) * 16;
    unsigned int xoff[12];
#pragma unroll
    for (int i = 0; i < 4; ++i)
#pragma unroll
        for (int q = 0; q < 3; ++q)
            xoff[i * 3 + q] = (unsigned int)(((g * 16 + b0 + i) * G3 + q * HH + (jj & ~1)) >> 1);
    const unsigned int XSTEP = (unsigned int)((BB * G3) >> 1);

    unsigned int xc[12];
#pragma unroll
    for (int v = 0; v < 12; ++v) xc[v] = xg32[xoff[v]];

    for (int t = 0; t < TT; ++t) {
        const unsigned int want = (unsigned int)t;
        const char* pb = pollb + (size_t)(t & 1) * PARITY_B;
        u32x4 P[16];
        while (true) {
            GLD16O(P[ 0], pb, "0");    GLD16O(P[ 1], pb, "128");
            GLD16O(P[ 2], pb, "256");  GLD16O(P[ 3], pb, "384");
            GLD16O(P[ 4], pb, "512");  GLD16O(P[ 5], pb, "640");
            GLD16O(P[ 6], pb, "768");  GLD16O(P[ 7], pb, "896");
            GLD16O(P[ 8], pb, "1024"); GLD16O(P[ 9], pb, "1152");
            GLD16O(P[10], pb, "1280"); GLD16O(P[11], pb, "1408");
            GLD16O(P[12], pb, "1536"); GLD16O(P[13], pb, "1664");
            GLD16O(P[14], pb, "1792"); GLD16O(P[15], pb, "1920");
            asm volatile("s_waitcnt vmcnt(0)" ::: "memory");
            __builtin_amdgcn_sched_barrier(0);
            bool ok = true;
#pragma unroll
            for (int ks = 0; ks < 16; ++ks)
                ok &= (P[ks][1] == want) & (P[ks][3] == want);
            if (ok) break;
        }

        unsigned int* hD = &hF[(t & 1) * 4096 + dstb];
#pragma unroll
        for (int ks = 0; ks < 16; ++ks) {
            unsigned long long dv = (unsigned long long)P[ks][0] |
                                    ((unsigned long long)P[ks][2] << 32);
            *(unsigned long long*)&hD[ks * 256] = dv;
        }

        unsigned int xn[12];
        {
            const unsigned int tw = (t < TT - 1 ? (unsigned int)(t + 1) : (unsigned int)t) * XSTEP;
#pragma unroll
            for (int v = 0; v < 12; ++v) xn[v] = xg32[xoff[v] + tw];
        }

        __syncthreads();

        const char* hA = (const char*)hF + (t & 1) * 16384 + lane * 16;
        f32x4 aR = (f32x4)(0.0f), aZ = (f32x4)(0.0f), aN = (f32x4)(0.0f);
#pragma unroll
        for (int ks = 0; ks < 16; ++ks) {
            short8 a = *(const short8*)(hA + ks * 1024);
            aR = __builtin_amdgcn_mfma_f32_16x16x32_bf16(a, Wr[0][ks], aR, 0, 0, 0);
            aZ = __builtin_amdgcn_mfma_f32_16x16x32_bf16(a, Wr[1][ks], aZ, 0, 0, 0);
            aN = __builtin_amdgcn_mfma_f32_16x16x32_bf16(a, Wr[2][ks], aN, 0, 0, 0);
        }

        const unsigned long long tag = ((unsigned long long)(t + 1)) << 32;
        unsigned long long* dst = hb64 + (size_t)((t + 1) & 1) * BB * 256;
#pragma unroll
        for (int i = 0; i < 4; ++i) {
            float xr = bf2f((unsigned short)(xc[i * 3 + 0] >> xsel));
            float xz = bf2f((unsigned short)(xc[i * 3 + 1] >> xsel));
            float xn_ = bf2f((unsigned short)(xc[i * 3 + 2] >> xsel));
            float r = sigmoidf_fast(xr + aR[i] + bhr);
            float z = sigmoidf_fast(xz + aZ[i] + bhz);
            float n = tanhf_fast(xn_ + r * (aN[i] + bhn));
            hh[i] = (1.0f - z) * n + z * hh[i];
            unsigned int u  = (unsigned int)f2bf(hh[i]);
            unsigned int pv = (unsigned int)__shfl_xor((int)u, 1);
            if ((lane & 1) == 0) {
                unsigned long long word = tag | (unsigned long long)(u | (pv << 16));
                __hip_atomic_store(&dst[(size_t)(g * 16 + b0 + i) * 256 + (jj >> 1)], word,
                                   __ATOMIC_RELAXED, __HIP_MEMORY_SCOPE_AGENT);
            }
        }

#pragma unroll
        for (int v = 0; v < 12; ++v) xc[v] = xn[v];
    }

#pragma unroll
    for (int i = 0; i < 4; ++i)
        out[(size_t)(g * 16 + b0 + i) * HH + jj] = hh[i];
}

// ---------------------------------------------------------------------------
// PROBE A: exchange skeleton only (poll + stage + barrier + tagged publish).
// Identical topology/mapping/addressing to gru_scan v5; zero compute.
// Own tagged buffer hbP (zero-initialized). Measures the protocol floor.
// ---------------------------------------------------------------------------
__global__ __launch_bounds__(NTH2, 1) void probe_comm(
    unsigned long long* __restrict__ hbP)     // [2][B][256] tagged pairs
{
    __shared__ unsigned int hF[2 * 4096];

    const int g    = blockIdx.x & 7;
    const int m    = blockIdx.x >> 3;
    const int tid  = threadIdx.x;
    const int lane = tid & 63;
    const int w    = tid >> 6;

    const int jj = m * 32 + w * 16 + (lane & 15);
    const int b0 = (lane >> 4) * 4;

    const int prow = tid & 15;
    const int plg  = (tid >> 4) & 3;
    const int pe2  = tid >> 6;
    const char* pollb = (const char*)hbP +
        (((size_t)g * 16 + prow) * 256 + plg * 4 + pe2 * 2) * 8;
    const size_t PARITY_B = (size_t)BB * 256 * 8;
    const int dstb = plg * 64 + prow * 4 + pe2 * 2;

    for (int t = 0; t < TT; ++t) {
        const unsigned int want = (unsigned int)t;
        const char* pb = pollb + (size_t)(t & 1) * PARITY_B;
        u32x4 P[16];
        while (true) {
            GLD16O(P[ 0], pb, "0");    GLD16O(P[ 1], pb, "128");
            GLD16O(P[ 2], pb, "256");  GLD16O(P[ 3], pb, "384");
            GLD16O(P[ 4], pb, "512");  GLD16O(P[ 5], pb, "640");
            GLD16O(P[ 6], pb, "768");  GLD16O(P[ 7], pb, "896");
            GLD16O(P[ 8], pb, "1024"); GLD16O(P[ 9], pb, "1152");
            GLD16O(P[10], pb, "1280"); GLD16O(P[11], pb, "1408");
            GLD16O(P[12], pb, "1536"); GLD16O(P[13], pb, "1664");
            GLD16O(P[14], pb, "1792"); GLD16O(P[15], pb, "1920");
            asm volatile("s_waitcnt vmcnt(0)" ::: "memory");
            __builtin_amdgcn_sched_barrier(0);
            bool ok = true;
#pragma unroll
            for (int ks = 0; ks < 16; ++ks)
                ok &= (P[ks][1] == want) & (P[ks][3] == want);
            if (ok) break;
        }

        unsigned int* hD = &hF[(t & 1) * 4096 + dstb];
#pragma unroll
        for (int ks = 0; ks < 16; ++ks) {
            unsigned long long dv = (unsigned long long)P[ks][0] |
                                    ((unsigned long long)P[ks][2] << 32);
            *(unsigned long long*)&hD[ks * 256] = dv;
        }

        __syncthreads();

        const unsigned long long tag = ((unsigned long long)(t + 1)) << 32;
        unsigned long long* dst = hbP + (size_t)((t + 1) & 1) * BB * 256;
#pragma unroll
        for (int i = 0; i < 4; ++i) {
            if ((lane & 1) == 0) {
                unsigned long long word = tag | 0x3f803f80ull;
                __hip_atomic_store(&dst[(size_t)(g * 16 + b0 + i) * 256 + (jj >> 1)], word,
                                   __ATOMIC_RELAXED, __HIP_MEMORY_SCOPE_AGENT);
            }
        }
    }
}

// ---------------------------------------------------------------------------
// PROBE B: local step skeleton only (stage-from-regs + barrier + xg loads +
// 48 MFMA + gates + private tagged stores). No cross-block dependency.
// Preserves v5's per-step instruction order. Measures local serial cost.
// ---------------------------------------------------------------------------
__global__ __launch_bounds__(NTH2, 1) void probe_comp(
    const unsigned short* __restrict__ xg,
    const float* __restrict__ Whh,
    const float* __restrict__ bhh,
    unsigned long long* __restrict__ hbC)     // private sink, [B][256]
{
    __shared__ unsigned int hF[2 * 4096];

    const int g    = blockIdx.x & 7;
    const int m    = blockIdx.x >> 3;
    const int tid  = threadIdx.x;
    const int lane = tid & 63;
    const int w    = tid >> 6;

    const int jj = m * 32 + w * 16 + (lane & 15);
    short8 Wr[3][16];
    {
        const int kofs = (lane >> 4) * 8;
#pragma unroll
        for (int q = 0; q < 3; ++q) {
            const float* wrow = Whh + ((size_t)(q * HH + jj)) * HH + kofs;
#pragma unroll
            for (int ks = 0; ks < 16; ++ks) {
                float4 v0 = *(const float4*)(wrow + ks * 32);
                float4 v1 = *(const float4*)(wrow + ks * 32 + 4);
                union { short8 s; unsigned int u[4]; } pk;
                pk.u[0] = (unsigned int)f2bf(v0.x) | ((unsigned int)f2bf(v0.y) << 16);
                pk.u[1] = (unsigned int)f2bf(v0.z) | ((unsigned int)f2bf(v0.w) << 16);
                pk.u[2] = (unsigned int)f2bf(v1.x) | ((unsigned int)f2bf(v1.y) << 16);
                pk.u[3] = (unsigned int)f2bf(v1.z) | ((unsigned int)f2bf(v1.w) << 16);
                Wr[q][ks] = pk.s;
            }
        }
    }

    const float bhr = bhh[jj];
    const float bhz = bhh[HH + jj];
    const float bhn = bhh[2 * HH + jj];
    const int b0 = (lane >> 4) * 4;

    float hh[4] = {0.0f, 0.0f, 0.0f, 0.0f};

    const int prow = tid & 15;
    const int plg  = (tid >> 4) & 3;
    const int pe2  = tid >> 6;
    const int dstb = plg * 64 + prow * 4 + pe2 * 2;

    const unsigned int* xg32 = (const unsigned int*)xg;
    const unsigned int xsel = (unsigned int)(jj & 1) * 16;
    unsigned int xoff[12];
#pragma unroll
    for (int i = 0; i < 4; ++i)
#pragma unroll
        for (int q = 0; q < 3; ++q)
            xoff[i * 3 + q] = (unsigned int)(((g * 16 + b0 + i) * G3 + q * HH + (jj & ~1)) >> 1);
    const unsigned int XSTEP = (unsigned int)((BB * G3) >> 1);

    unsigned int xc[12];
#pragma unroll
    for (int v = 0; v < 12; ++v) xc[v] = xg32[xoff[v]];

    // fake P content (from Wr bits) — values irrelevant, dependencies real
    u32x4 P[16];
#pragma unroll
    for (int ks = 0; ks < 16; ++ks) {
        union { short8 s; u32x4 u; } c; c.s = Wr[0][ks]; P[ks] = c.u;
    }

    for (int t = 0; t < TT; ++t) {
        unsigned int* hD = &hF[(t & 1) * 4096 + dstb];
#pragma unroll
        for (int ks = 0; ks < 16; ++ks) {
            unsigned long long dv = (unsigned long long)P[ks][0] |
                                    ((unsigned long long)P[ks][2] << 32);
            *(unsigned long long*)&hD[ks * 256] = dv;
        }

        unsigned int xn[12];
        {
            const unsigned int tw = (t < TT - 1 ? (unsigned int)(t + 1) : (unsigned int)t) * XSTEP;
#pragma unroll
            for (int v = 0; v < 12; ++v) xn[v] = xg32[xoff[v] + tw];
        }

        __syncthreads();

        const char* hA = (const char*)hF + (t & 1) * 16384 + lane * 16;
        f32x4 aR = (f32x4)(0.0f), aZ = (f32x4)(0.0f), aN = (f32x4)(0.0f);
#pragma unroll
        for (int ks = 0; ks < 16; ++ks) {
            short8 a = *(const short8*)(hA + ks * 1024);
            aR = __builtin_amdgcn_mfma_f32_16x16x32_bf16(a, Wr[0][ks], aR, 0, 0, 0);
            aZ = __builtin_amdgcn_mfma_f32_16x16x32_bf16(a, Wr[1][ks], aZ, 0, 0, 0);
            aN = __builtin_amdgcn_mfma_f32_16x16x32_bf16(a, Wr[2][ks], aN, 0, 0, 0);
        }

        const unsigned long long tag = ((unsigned long long)(t + 1)) << 32;
#pragma unroll
        for (int i = 0; i < 4; ++i) {
            float xr = bf2f((unsigned short)(xc[i * 3 + 0] >> xsel));
            float xz = bf2f((unsigned short)(xc[i * 3 + 1] >> xsel));
            float xn_ = bf2f((unsigned short)(xc[i * 3 + 2] >> xsel));
            float r = sigmoidf_fast(xr + aR[i] + bhr);
            float z = sigmoidf_fast(xz + aZ[i] + bhz);
            float n = tanhf_fast(xn_ + r * (aN[i] + bhn));
            hh[i] = (1.0f - z) * n + z * hh[i];
            unsigned int u  = (unsigned int)f2bf(hh[i]);
            unsigned int pv = (unsigned int)__shfl_xor((int)u, 1);
            if ((lane & 1) == 0) {
                unsigned long long word = tag | (unsigned long long)(u | (pv << 16));
                __hip_atomic_store(&hbC[(size_t)(g * 16 + b0 + i) * 256 + (jj >> 1)], word,
                                   __ATOMIC_RELAXED, __HIP_MEMORY_SCOPE_AGENT);
            }
        }

#pragma unroll
        for (int v = 0; v < 12; ++v) xc[v] = xn[v];
    }
}

// ---------------------------------------------------------------------------
extern "C" void kernel_launch(void* const* d_in, const int* in_sizes, int n_in,
                              void* d_out, int out_size, void* d_ws, size_t ws_size,
                              hipStream_t stream) {
    const float* x   = (const float*)d_in[0];
    const float* Wih = (const float*)d_in[1];
    const float* Whh = (const float*)d_in[2];
    const float* bih = (const float*)d_in[3];
    const float* bhh = (const float*)d_in[4];
    float* out = (float*)d_out;

    const size_t XG_BYTES   = (size_t)TT * BB * G3 * 2;        // 192 MiB bf16
    const size_t HB_BYTES   = (size_t)2 * BB * 256 * 8;        // 512 KiB
    unsigned short* xg       = (unsigned short*)d_ws;
    unsigned long long* hb64 = (unsigned long long*)((char*)d_ws + XG_BYTES);
    unsigned long long* hbP  = (unsigned long long*)((char*)d_ws + XG_BYTES + HB_BYTES);
    unsigned long long* hbC  = (unsigned long long*)((char*)d_ws + XG_BYTES + 2 * HB_BYTES);

    // zero real + probe tagged buffers (tag 0 == valid h(0) = 0)
    hipMemsetAsync((char*)d_ws + XG_BYTES, 0, 2 * HB_BYTES, stream);

    dim3 g1(G3 / 128, TT);
    xgate_gemm<<<g1, 256, 0, stream>>>(x, Wih, bih, xg);

    gru_scan<<<128, NTH2, 0, stream>>>(xg, Whh, bhh, out, hb64);

    // ---- ablation probes (disjoint scratch; do not affect d_out) ----
    probe_comm<<<128, NTH2, 0, stream>>>(hbP);
    probe_comp<<<128, NTH2, 0, stream>>>(xg, Whh, bhh, hbC);
}

// Round 9
// 2832.323 us; speedup vs baseline: 1.5382x; 1.5382x over previous
//
#include <hip/hip_runtime.h>
#include <hip/hip_bf16.h>

#define BB   128   // batch
#define TT   512   // seq len
#define II   256   // input dim
#define HH   512   // hidden dim
#define G3   1536  // 3*H

typedef __attribute__((ext_vector_type(8))) short short8;
typedef __attribute__((ext_vector_type(4))) float f32x4;
typedef __attribute__((ext_vector_type(4))) unsigned int u32x4;

__device__ __forceinline__ float bf2f(unsigned short u) {
    union { unsigned int u; float f; } p; p.u = ((unsigned int)u) << 16; return p.f;
}
__device__ __forceinline__ unsigned short f2bf(float f) {
    union { float f; unsigned int u; } p; p.f = f;
    unsigned int r = p.u + 0x7fffu + ((p.u >> 16) & 1u);  // RNE
    return (unsigned short)(r >> 16);
}
__device__ __forceinline__ float sigmoidf_fast(float x) {
    return 1.0f / (1.0f + __expf(-x));
}
__device__ __forceinline__ float tanhf_fast(float x) {
    return 1.0f - 2.0f / (1.0f + __expf(2.0f * x));
}

// coherent 16B load with literal offset (bypass L1/L2: remote stores visible).
// Caller must s_waitcnt vmcnt(0) + sched_barrier(0) before using dst (rule #18).
#define GLD16O(dst, base, OFFSTR)                                         \
    asm volatile("global_load_dwordx4 %0, %1, off offset:" OFFSTR " sc0 sc1" \
                 : "=v"(dst) : "v"(base))

// ---------------------------------------------------------------------------
// Kernel 1: xg[t][b][g] = bf16( x[b,t,:] @ W_ih[g,:] + b_ih[g] )   (unchanged)
// ---------------------------------------------------------------------------
__global__ __launch_bounds__(256) void xgate_gemm(
    const float* __restrict__ x,       // [B,T,I]
    const float* __restrict__ Wih,     // [1536,256]
    const float* __restrict__ bih,     // [1536]
    unsigned short* __restrict__ xg)   // [T,B,1536] bf16
{
    __shared__ unsigned short AS[128][40];
    __shared__ unsigned short BS[128][40];

    const int t   = blockIdx.y;
    const int g0  = blockIdx.x * 128;
    const int tid = threadIdx.x;
    const int lane = tid & 63;
    const int w    = tid >> 6;
    const int wr   = w >> 1, wc = w & 1;

    f32x4 acc[4][4];
#pragma unroll
    for (int a = 0; a < 4; ++a)
#pragma unroll
        for (int b = 0; b < 4; ++b) acc[a][b] = (f32x4)(0.0f);

    for (int kk = 0; kk < 8; ++kk) {
        const int k0 = kk * 32;
#pragma unroll
        for (int ii = 0; ii < 4; ++ii) {
            int slot = tid + 256 * ii;
            int row  = slot >> 3;
            int c4   = slot & 7;
            float4 av = *(const float4*)(x + ((size_t)row * TT + t) * II + k0 + c4 * 4);
            unsigned short* ap = &AS[row][c4 * 4];
            ap[0] = f2bf(av.x); ap[1] = f2bf(av.y); ap[2] = f2bf(av.z); ap[3] = f2bf(av.w);
            float4 bv = *(const float4*)(Wih + (size_t)(g0 + row) * II + k0 + c4 * 4);
            unsigned short* bp = &BS[row][c4 * 4];
            bp[0] = f2bf(bv.x); bp[1] = f2bf(bv.y); bp[2] = f2bf(bv.z); bp[3] = f2bf(bv.w);
        }
        __syncthreads();

        const int kc = (lane >> 4) * 8;
        short8 a[4], b[4];
#pragma unroll
        for (int mi = 0; mi < 4; ++mi)
            a[mi] = *(const short8*)&AS[wr * 64 + mi * 16 + (lane & 15)][kc];
#pragma unroll
        for (int ni = 0; ni < 4; ++ni)
            b[ni] = *(const short8*)&BS[wc * 64 + ni * 16 + (lane & 15)][kc];
#pragma unroll
        for (int mi = 0; mi < 4; ++mi)
#pragma unroll
            for (int ni = 0; ni < 4; ++ni)
                acc[mi][ni] = __builtin_amdgcn_mfma_f32_16x16x32_bf16(a[mi], b[ni], acc[mi][ni], 0, 0, 0);
        __syncthreads();
    }

#pragma unroll
    for (int ni = 0; ni < 4; ++ni) {
        const int col = wc * 64 + ni * 16 + (lane & 15);
        const float bias = bih[g0 + col];
#pragma unroll
        for (int mi = 0; mi < 4; ++mi) {
#pragma unroll
            for (int i = 0; i < 4; ++i) {
                const int row = wr * 64 + mi * 16 + (lane >> 4) * 4 + i;
                xg[((size_t)t * BB + row) * G3 + g0 + col] = f2bf(acc[mi][ni][i] + bias);
            }
        }
    }
}

// ---------------------------------------------------------------------------
// Kernel 2 v7: 32 blocks x 512 thr = 8 groups (16 batch rows) x 4 members
// (128 h-dims). 8 waves/block; wave w owns j = m*128 + w*16 .. +15, W in
// regs (192 VGPR/lane). Tagged u64 parity exchange (unchanged induction).
// Per step: poll 4 dwordx4/thread -> detect -> issue 12 xg loads (consumed
// THIS step; latency hides under stage+barrier+MFMA; barrier drains lgkm
// ONLY, not vmcnt) -> stage 2 b128 -> s_barrier -> 48 MFMA -> gates ->
// tagged publish.
// ---------------------------------------------------------------------------
#define NTH2 512

__global__ __launch_bounds__(NTH2, 1) void gru_scan(
    const unsigned short* __restrict__ xg,    // [T,B,1536] bf16
    const float* __restrict__ Whh,            // [1536,512]
    const float* __restrict__ bhh,            // [1536]
    float* __restrict__ out,                  // [B,H]
    unsigned long long* __restrict__ hb64)    // [2][B][256] tagged pairs
{
    __shared__ unsigned int hF[2 * 4096];     // 32 KiB, [parity][ks][1024B frag]

    const int g    = blockIdx.x & 7;     // group: batch rows 16g..16g+15
    const int m    = blockIdx.x >> 3;    // member: h dims 128m..128m+127
    const int tid  = threadIdx.x;
    const int lane = tid & 63;
    const int w    = tid >> 6;           // wave 0..7

    // ---- W_hh slice -> registers (B-fragment order), one-time ----
    const int jj = m * 128 + w * 16 + (lane & 15);  // this lane's global j
    short8 Wr[3][16];
    {
        const int kofs = (lane >> 4) * 8;
#pragma unroll
        for (int q = 0; q < 3; ++q) {
            const float* wrow = Whh + ((size_t)(q * HH + jj)) * HH + kofs;
#pragma unroll
            for (int ks = 0; ks < 16; ++ks) {
                float4 v0 = *(const float4*)(wrow + ks * 32);
                float4 v1 = *(const float4*)(wrow + ks * 32 + 4);
                union { short8 s; unsigned int u[4]; } pk;
                pk.u[0] = (unsigned int)f2bf(v0.x) | ((unsigned int)f2bf(v0.y) << 16);
                pk.u[1] = (unsigned int)f2bf(v0.z) | ((unsigned int)f2bf(v0.w) << 16);
                pk.u[2] = (unsigned int)f2bf(v1.x) | ((unsigned int)f2bf(v1.y) << 16);
                pk.u[3] = (unsigned int)f2bf(v1.z) | ((unsigned int)f2bf(v1.w) << 16);
                Wr[q][ks] = pk.s;
            }
        }
    }

    const float bhr = bhh[jj];
    const float bhz = bhh[HH + jj];
    const float bhn = bhh[2 * HH + jj];
    const int b0 = (lane >> 4) * 4;                 // first of 4 batch rows

    float hh[4] = {0.0f, 0.0f, 0.0f, 0.0f};        // carried fp32 state

    // ---- poll/stage ownership (512 thr): row = tid&15, lg = (tid>>4)&3,
    //      ksh = tid>>6 (0..7) -> ks in {2ksh, 2ksh+1}
    //   src bytes: row*2048 + ksh*256 + lg*32  (+0,+16 = ks even; +128,+144 odd)
    //   dst bytes: ksh*2048 + lg*256 + row*16  (+1024 for odd ks)  [b128, CF]
    const int prow = tid & 15;
    const int plg  = (tid >> 4) & 3;
    const int pksh = tid >> 6;
    const char* pollb = (const char*)hb64 +
        ((size_t)g * 16 + prow) * 2048 + pksh * 256 + plg * 32;
    const size_t PARITY_B = (size_t)BB * 256 * 8;
    const int dstbyte = pksh * 2048 + plg * 256 + prow * 16;

    // ---- xg addressing (u32 words) ----
    const unsigned int* xg32 = (const unsigned int*)xg;
    const unsigned int xsel = (unsigned int)(jj & 1) * 16;
    unsigned int xoff[12];
#pragma unroll
    for (int i = 0; i < 4; ++i)
#pragma unroll
        for (int q = 0; q < 3; ++q)
            xoff[i * 3 + q] = (unsigned int)(((g * 16 + b0 + i) * G3 + q * HH + (jj & ~1)) >> 1);
    const unsigned int XSTEP = (unsigned int)((BB * G3) >> 1);  // u32 words per t

    const unsigned int* xgp = xg32;   // advanced by XSTEP per step

    for (int t = 0; t < TT; ++t) {
        // ---- poll own 4 quads (data IS the flag) ----
        const unsigned int want = (unsigned int)t;
        const char* pb = pollb + (size_t)(t & 1) * PARITY_B;
        u32x4 Pa0, Pa1, Pb0, Pb1;
        while (true) {
            GLD16O(Pa0, pb, "0");   GLD16O(Pa1, pb, "16");
            GLD16O(Pb0, pb, "128"); GLD16O(Pb1, pb, "144");
            asm volatile("s_waitcnt vmcnt(0)" ::: "memory");
            __builtin_amdgcn_sched_barrier(0);
            bool ok = (Pa0[1] == want) & (Pa0[3] == want) &
                      (Pa1[1] == want) & (Pa1[3] == want) &
                      (Pb0[1] == want) & (Pb0[3] == want) &
                      (Pb1[1] == want) & (Pb1[3] == want);
            if (__all(ok)) break;
        }

        // ---- issue xg loads for THIS step (consumed after MFMA; latency
        //      hides under stage + barrier + MFMA; barrier is lgkm-only) ----
        unsigned int xc[12];
#pragma unroll
        for (int v = 0; v < 12; ++v) xc[v] = xgp[xoff[v]];

        // ---- stage 2 x b128 to LDS A-fragment layout (conflict-free) ----
        {
            char* hD = (char*)hF + (t & 1) * 16384 + dstbyte;
            u32x4 A; A[0] = Pa0[0]; A[1] = Pa0[2]; A[2] = Pa1[0]; A[3] = Pa1[2];
            *(u32x4*)hD = A;
            u32x4 B; B[0] = Pb0[0]; B[1] = Pb0[2]; B[2] = Pb1[0]; B[3] = Pb1[2];
            *(u32x4*)(hD + 1024) = B;
        }

        // ---- block barrier: drain LDS writes only (NOT vmcnt) ----
        asm volatile("s_waitcnt lgkmcnt(0)" ::: "memory");
        __builtin_amdgcn_s_barrier();

        // ---- MFMA: 3 gates x K=512; A from LDS, B from registers ----
        const char* hA = (const char*)hF + (t & 1) * 16384 + lane * 16;
        f32x4 aR = (f32x4)(0.0f), aZ = (f32x4)(0.0f), aN = (f32x4)(0.0f);
#pragma unroll
        for (int ks = 0; ks < 16; ++ks) {
            short8 a = *(const short8*)(hA + ks * 1024);
            aR = __builtin_amdgcn_mfma_f32_16x16x32_bf16(a, Wr[0][ks], aR, 0, 0, 0);
            aZ = __builtin_amdgcn_mfma_f32_16x16x32_bf16(a, Wr[1][ks], aZ, 0, 0, 0);
            aN = __builtin_amdgcn_mfma_f32_16x16x32_bf16(a, Wr[2][ks], aN, 0, 0, 0);
        }

        // ---- gates in-register; tagged publish ----
        const unsigned long long tag = ((unsigned long long)(t + 1)) << 32;
        unsigned long long* dst = hb64 + (size_t)((t + 1) & 1) * BB * 256;
#pragma unroll
        for (int i = 0; i < 4; ++i) {
            float xr  = bf2f((unsigned short)(xc[i * 3 + 0] >> xsel));
            float xz  = bf2f((unsigned short)(xc[i * 3 + 1] >> xsel));
            float xnv = bf2f((unsigned short)(xc[i * 3 + 2] >> xsel));
            float r = sigmoidf_fast(xr + aR[i] + bhr);
            float z = sigmoidf_fast(xz + aZ[i] + bhz);
            float n = tanhf_fast(xnv + r * (aN[i] + bhn));
            hh[i] = (1.0f - z) * n + z * hh[i];
            unsigned int u  = (unsigned int)f2bf(hh[i]);
            unsigned int pv = (unsigned int)__shfl_xor((int)u, 1);
            if ((lane & 1) == 0) {
                unsigned long long word = tag | (unsigned long long)(u | (pv << 16));
                __hip_atomic_store(&dst[(size_t)(g * 16 + b0 + i) * 256 + (jj >> 1)], word,
                                   __ATOMIC_RELAXED, __HIP_MEMORY_SCOPE_AGENT);
            }
        }

        xgp += XSTEP;
    }

    // ---- final state ----
#pragma unroll
    for (int i = 0; i < 4; ++i)
        out[(size_t)(g * 16 + b0 + i) * HH + jj] = hh[i];
}

// ---------------------------------------------------------------------------
extern "C" void kernel_launch(void* const* d_in, const int* in_sizes, int n_in,
                              void* d_out, int out_size, void* d_ws, size_t ws_size,
                              hipStream_t stream) {
    const float* x   = (const float*)d_in[0];
    const float* Wih = (const float*)d_in[1];
    const float* Whh = (const float*)d_in[2];
    const float* bih = (const float*)d_in[3];
    const float* bhh = (const float*)d_in[4];
    float* out = (float*)d_out;

    const size_t XG_BYTES   = (size_t)TT * BB * G3 * 2;        // 192 MiB bf16
    unsigned short* xg       = (unsigned short*)d_ws;
    unsigned long long* hb64 = (unsigned long long*)((char*)d_ws + XG_BYTES);
    const size_t HB_BYTES   = (size_t)2 * BB * 256 * 8;        // 512 KiB

    // tags must start at 0 (= h(0) valid, value 0)
    hipMemsetAsync((char*)d_ws + XG_BYTES, 0, HB_BYTES, stream);

    dim3 g1(G3 / 128, TT);
    xgate_gemm<<<g1, 256, 0, stream>>>(x, Wih, bih, xg);

    gru_scan<<<32, NTH2, 0, stream>>>(xg, Whh, bhh, out, hb64);
}

// Round 11
// 2484.185 us; speedup vs baseline: 1.7538x; 1.1401x over previous
//
#include <hip/hip_runtime.h>
#include <hip/hip_bf16.h>

#define BB   128   // batch
#define TT   512   // seq len
#define II   256   // input dim
#define HH   512   // hidden dim
#define G3   1536  // 3*H

typedef __attribute__((ext_vector_type(8))) short short8;
typedef __attribute__((ext_vector_type(4))) float f32x4;
typedef __attribute__((ext_vector_type(4))) unsigned int u32x4;

__device__ __forceinline__ float bf2f(unsigned short u) {
    union { unsigned int u; float f; } p; p.u = ((unsigned int)u) << 16; return p.f;
}
__device__ __forceinline__ unsigned short f2bf(float f) {
    union { float f; unsigned int u; } p; p.f = f;
    unsigned int r = p.u + 0x7fffu + ((p.u >> 16) & 1u);  // RNE
    return (unsigned short)(r >> 16);
}
__device__ __forceinline__ float sigmoidf_fast(float x) {
    return 1.0f / (1.0f + __expf(-x));
}
__device__ __forceinline__ float tanhf_fast(float x) {
    return 1.0f - 2.0f / (1.0f + __expf(2.0f * x));
}

// coherent 16B load with literal offset (bypass L1/L2: remote stores visible).
// Caller must s_waitcnt vmcnt(0) + sched_barrier(0) before using dst (rule #18).
#define GLD16O(dst, base, OFFSTR)                                         \
    asm volatile("global_load_dwordx4 %0, %1, off offset:" OFFSTR " sc0 sc1" \
                 : "=v"(dst) : "v"(base))

// ---------------------------------------------------------------------------
// Kernel 1: xg[t][b][g] = bf16( x[b,t,:] @ W_ih[g,:] + b_ih[g] )   (unchanged)
// ---------------------------------------------------------------------------
__global__ __launch_bounds__(256) void xgate_gemm(
    const float* __restrict__ x,       // [B,T,I]
    const float* __restrict__ Wih,     // [1536,256]
    const float* __restrict__ bih,     // [1536]
    unsigned short* __restrict__ xg)   // [T,B,1536] bf16
{
    __shared__ unsigned short AS[128][40];
    __shared__ unsigned short BS[128][40];

    const int t   = blockIdx.y;
    const int g0  = blockIdx.x * 128;
    const int tid = threadIdx.x;
    const int lane = tid & 63;
    const int w    = tid >> 6;
    const int wr   = w >> 1, wc = w & 1;

    f32x4 acc[4][4];
#pragma unroll
    for (int a = 0; a < 4; ++a)
#pragma unroll
        for (int b = 0; b < 4; ++b) acc[a][b] = (f32x4)(0.0f);

    for (int kk = 0; kk < 8; ++kk) {
        const int k0 = kk * 32;
#pragma unroll
        for (int ii = 0; ii < 4; ++ii) {
            int slot = tid + 256 * ii;
            int row  = slot >> 3;
            int c4   = slot & 7;
            float4 av = *(const float4*)(x + ((size_t)row * TT + t) * II + k0 + c4 * 4);
            unsigned short* ap = &AS[row][c4 * 4];
            ap[0] = f2bf(av.x); ap[1] = f2bf(av.y); ap[2] = f2bf(av.z); ap[3] = f2bf(av.w);
            float4 bv = *(const float4*)(Wih + (size_t)(g0 + row) * II + k0 + c4 * 4);
            unsigned short* bp = &BS[row][c4 * 4];
            bp[0] = f2bf(bv.x); bp[1] = f2bf(bv.y); bp[2] = f2bf(bv.z); bp[3] = f2bf(bv.w);
        }
        __syncthreads();

        const int kc = (lane >> 4) * 8;
        short8 a[4], b[4];
#pragma unroll
        for (int mi = 0; mi < 4; ++mi)
            a[mi] = *(const short8*)&AS[wr * 64 + mi * 16 + (lane & 15)][kc];
#pragma unroll
        for (int ni = 0; ni < 4; ++ni)
            b[ni] = *(const short8*)&BS[wc * 64 + ni * 16 + (lane & 15)][kc];
#pragma unroll
        for (int mi = 0; mi < 4; ++mi)
#pragma unroll
            for (int ni = 0; ni < 4; ++ni)
                acc[mi][ni] = __builtin_amdgcn_mfma_f32_16x16x32_bf16(a[mi], b[ni], acc[mi][ni], 0, 0, 0);
        __syncthreads();
    }

#pragma unroll
    for (int ni = 0; ni < 4; ++ni) {
        const int col = wc * 64 + ni * 16 + (lane & 15);
        const float bias = bih[g0 + col];
#pragma unroll
        for (int mi = 0; mi < 4; ++mi) {
#pragma unroll
            for (int i = 0; i < 4; ++i) {
                const int row = wr * 64 + mi * 16 + (lane >> 4) * 4 + i;
                xg[((size_t)t * BB + row) * G3 + g0 + col] = f2bf(acc[mi][ni][i] + bias);
            }
        }
    }
}

// ---------------------------------------------------------------------------
// Kernel 2 v8 = v5 topology (128 blocks x 2 waves, 8 groups x 16 members,
// W in regs, tagged u64 parity exchange) + two evidence-backed fixes:
//  FIX1: xg loads issued AFTER __syncthreads (consumed next step; drained by
//        next poll's vmcnt(0)) -> no HBM stall inside the barrier. Unroll-2
//        with xcA/xcB so indices stay compile-time (rule #20).
//  FIX2: stage ownership re-mapped to full 16B slots per thread
//        (b128 writes, conflict-free; same final LDS layout as v5):
//        thread (prow=tid&15, plg=(tid>>4)&3, w=tid>>6) polls, for
//        ks' = 0..7 (ks = w*8+ks'): quads at row prow, bytes
//        ks*128 + plg*32 + {0,16}; writes slot (plg*16+prow) at ks*1024.
// Everything else bit-identical to v5 (1590 us base).
// ---------------------------------------------------------------------------
#define NTH2 128

__global__ __launch_bounds__(NTH2, 1) void gru_scan(
    const unsigned short* __restrict__ xg,    // [T,B,1536] bf16
    const float* __restrict__ Whh,            // [1536,512]
    const float* __restrict__ bhh,            // [1536]
    float* __restrict__ out,                  // [B,H]
    unsigned long long* __restrict__ hb64)    // [2][B][256] tagged pairs
{
    __shared__ unsigned int hF[2 * 4096];     // 32 KiB, [parity][ks][1024B frag]

    const int g    = blockIdx.x & 7;     // group: batch rows 16g..16g+15
    const int m    = blockIdx.x >> 3;    // member: h dims 32m..32m+31
    const int tid  = threadIdx.x;
    const int lane = tid & 63;
    const int w    = tid >> 6;           // wave 0/1: j half-tile + ks-half

    // ---- W_hh slice -> registers (B-fragment order), one-time ----
    const int jj = m * 32 + w * 16 + (lane & 15);   // this lane's global j
    short8 Wr[3][16];
    {
        const int kofs = (lane >> 4) * 8;
#pragma unroll
        for (int q = 0; q < 3; ++q) {
            const float* wrow = Whh + ((size_t)(q * HH + jj)) * HH + kofs;
#pragma unroll
            for (int ks = 0; ks < 16; ++ks) {
                float4 v0 = *(const float4*)(wrow + ks * 32);
                float4 v1 = *(const float4*)(wrow + ks * 32 + 4);
                union { short8 s; unsigned int u[4]; } pk;
                pk.u[0] = (unsigned int)f2bf(v0.x) | ((unsigned int)f2bf(v0.y) << 16);
                pk.u[1] = (unsigned int)f2bf(v0.z) | ((unsigned int)f2bf(v0.w) << 16);
                pk.u[2] = (unsigned int)f2bf(v1.x) | ((unsigned int)f2bf(v1.y) << 16);
                pk.u[3] = (unsigned int)f2bf(v1.z) | ((unsigned int)f2bf(v1.w) << 16);
                Wr[q][ks] = pk.s;
            }
        }
    }

    const float bhr = bhh[jj];
    const float bhz = bhh[HH + jj];
    const float bhn = bhh[2 * HH + jj];
    const int b0 = (lane >> 4) * 4;                 // first of 4 batch rows

    float hh[4] = {0.0f, 0.0f, 0.0f, 0.0f};        // carried fp32 state

    // ---- FIX2 ownership: full-slot staging ----
    const int prow = tid & 15;
    const int plg  = (tid >> 4) & 3;
    const char* pollb = (const char*)hb64 +
        ((size_t)g * 16 + prow) * 2048 + (size_t)w * 1024 + plg * 32;
    const size_t PARITY_B = (size_t)BB * 256 * 8;
    const int dstbyte = w * 8192 + (plg * 16 + prow) * 16;   // + ks'*1024

    // ---- xg addressing (u32 words) ----
    const unsigned int* xg32 = (const unsigned int*)xg;
    const unsigned int xsel = (unsigned int)(jj & 1) * 16;
    unsigned int xoff[12];
#pragma unroll
    for (int i = 0; i < 4; ++i)
#pragma unroll
        for (int q = 0; q < 3; ++q)
            xoff[i * 3 + q] = (unsigned int)(((g * 16 + b0 + i) * G3 + q * HH + (jj & ~1)) >> 1);
    const unsigned int XSTEP = (unsigned int)((BB * G3) >> 1);  // u32 words per t

    unsigned int xcA[12], xcB[12];
#pragma unroll
    for (int v = 0; v < 12; ++v) xcA[v] = xg32[xoff[v]];   // t = 0

#define STEP(T, PAR, XC, XN)                                                   \
    {                                                                          \
        const unsigned int want = (unsigned int)(T);                           \
        const char* pb = pollb + (size_t)(PAR) * PARITY_B;                     \
        u32x4 Q[16];                                                           \
        while (true) {                                                         \
            GLD16O(Q[ 0], pb, "0");   GLD16O(Q[ 1], pb, "16");                 \
            GLD16O(Q[ 2], pb, "128"); GLD16O(Q[ 3], pb, "144");                \
            GLD16O(Q[ 4], pb, "256"); GLD16O(Q[ 5], pb, "272");                \
            GLD16O(Q[ 6], pb, "384"); GLD16O(Q[ 7], pb, "400");                \
            GLD16O(Q[ 8], pb, "512"); GLD16O(Q[ 9], pb, "528");                \
            GLD16O(Q[10], pb, "640"); GLD16O(Q[11], pb, "656");                \
            GLD16O(Q[12], pb, "768"); GLD16O(Q[13], pb, "784");                \
            GLD16O(Q[14], pb, "896"); GLD16O(Q[15], pb, "912");                \
            asm volatile("s_waitcnt vmcnt(0)" ::: "memory");                   \
            __builtin_amdgcn_sched_barrier(0);                                 \
            bool ok = true;                                                    \
            _Pragma("unroll")                                                  \
            for (int j = 0; j < 16; ++j)                                       \
                ok &= (Q[j][1] == want) & (Q[j][3] == want);                   \
            if (ok) break;                                                     \
        }                                                                      \
        {   /* FIX2: conflict-free b128 full-slot stage */                     \
            char* hD = (char*)hF + (PAR) * 16384 + dstbyte;                    \
            _Pragma("unroll")                                                  \
            for (int k2 = 0; k2 < 8; ++k2) {                                   \
                u32x4 A;                                                       \
                A[0] = Q[2 * k2][0];     A[1] = Q[2 * k2][2];                  \
                A[2] = Q[2 * k2 + 1][0]; A[3] = Q[2 * k2 + 1][2];              \
                *(u32x4*)(hD + k2 * 1024) = A;                                 \
            }                                                                  \
        }                                                                      \
        __syncthreads();                                                       \
        {   /* FIX1: xg for T+1 issued AFTER barrier */                        \
            const unsigned int tw =                                            \
                ((T) < TT - 1 ? (unsigned int)(T) + 1u : (unsigned int)(T)) * XSTEP; \
            _Pragma("unroll")                                                  \
            for (int v = 0; v < 12; ++v) XN[v] = xg32[xoff[v] + tw];           \
        }                                                                      \
        const char* hA = (const char*)hF + (PAR) * 16384 + lane * 16;          \
        f32x4 aR = (f32x4)(0.0f), aZ = (f32x4)(0.0f), aN = (f32x4)(0.0f);      \
        _Pragma("unroll")                                                      \
        for (int ks = 0; ks < 16; ++ks) {                                      \
            short8 a = *(const short8*)(hA + ks * 1024);                       \
            aR = __builtin_amdgcn_mfma_f32_16x16x32_bf16(a, Wr[0][ks], aR, 0, 0, 0); \
            aZ = __builtin_amdgcn_mfma_f32_16x16x32_bf16(a, Wr[1][ks], aZ, 0, 0, 0); \
            aN = __builtin_amdgcn_mfma_f32_16x16x32_bf16(a, Wr[2][ks], aN, 0, 0, 0); \
        }                                                                      \
        const unsigned long long tag = ((unsigned long long)((T) + 1)) << 32;  \
        unsigned long long* dst = hb64 + (size_t)(((T) + 1) & 1) * BB * 256;   \
        _Pragma("unroll")                                                      \
        for (int i = 0; i < 4; ++i) {                                          \
            float xr  = bf2f((unsigned short)(XC[i * 3 + 0] >> xsel));         \
            float xz  = bf2f((unsigned short)(XC[i * 3 + 1] >> xsel));         \
            float xnv = bf2f((unsigned short)(XC[i * 3 + 2] >> xsel));         \
            float r = sigmoidf_fast(xr + aR[i] + bhr);                         \
            float z = sigmoidf_fast(xz + aZ[i] + bhz);                         \
            float n = tanhf_fast(xnv + r * (aN[i] + bhn));                     \
            hh[i] = (1.0f - z) * n + z * hh[i];                                \
            unsigned int u  = (unsigned int)f2bf(hh[i]);                       \
            unsigned int pv = (unsigned int)__shfl_xor((int)u, 1);             \
            if ((lane & 1) == 0) {                                             \
                unsigned long long word = tag | (unsigned long long)(u | (pv << 16)); \
                __hip_atomic_store(&dst[(size_t)(g * 16 + b0 + i) * 256 + (jj >> 1)], \
                                   word, __ATOMIC_RELAXED, __HIP_MEMORY_SCOPE_AGENT); \
            }                                                                  \
        }                                                                      \
    }

    for (int s = 0; s < TT / 2; ++s) {
        const int t0 = 2 * s;
        STEP(t0,     0, xcA, xcB);
        STEP(t0 + 1, 1, xcB, xcA);
    }
#undef STEP

    // ---- final state ----
#pragma unroll
    for (int i = 0; i < 4; ++i)
        out[(size_t)(g * 16 + b0 + i) * HH + jj] = hh[i];
}

// ---------------------------------------------------------------------------
extern "C" void kernel_launch(void* const* d_in, const int* in_sizes, int n_in,
                              void* d_out, int out_size, void* d_ws, size_t ws_size,
                              hipStream_t stream) {
    const float* x   = (const float*)d_in[0];
    const float* Wih = (const float*)d_in[1];
    const float* Whh = (const float*)d_in[2];
    const float* bih = (const float*)d_in[3];
    const float* bhh = (const float*)d_in[4];
    float* out = (float*)d_out;

    const size_t XG_BYTES   = (size_t)TT * BB * G3 * 2;        // 192 MiB bf16
    unsigned short* xg       = (unsigned short*)d_ws;
    unsigned long long* hb64 = (unsigned long long*)((char*)d_ws + XG_BYTES);
    const size_t HB_BYTES   = (size_t)2 * BB * 256 * 8;        // 512 KiB

    // tags must start at 0 (= h(0) valid, value 0)
    hipMemsetAsync((char*)d_ws + XG_BYTES, 0, HB_BYTES, stream);

    dim3 g1(G3 / 128, TT);
    xgate_gemm<<<g1, 256, 0, stream>>>(x, Wih, bih, xg);

    gru_scan<<<128, NTH2, 0, stream>>>(xg, Whh, bhh, out, hb64);
}